// Round 12
// baseline (558.237 us; speedup 1.0000x reference)
//
#include <hip/hip_runtime.h>
#include <hip/hip_bf16.h>

#define B 128
#define N 2048
#define E 16384
#define F 32
#define H 64
#define OUTD 16
#define CAP 16

typedef __attribute__((ext_vector_type(8))) short bf16x8;
typedef __attribute__((ext_vector_type(4))) float f32x4;

__device__ __forceinline__ float b2f(unsigned short u) {
    return __uint_as_float(((unsigned int)u) << 16);
}
__device__ __forceinline__ unsigned short f2b(float f) {
    unsigned int x = __float_as_uint(f);
    unsigned int r = (x + 0x7FFFu + ((x >> 16) & 1u)) >> 16;  // RNE, finite
    return (unsigned short)r;
}
__device__ __forceinline__ unsigned int pack2(float a, float b) {
    return (unsigned int)f2b(a) | ((unsigned int)f2b(b) << 16);
}

struct PrepArgs {
    const void* src[9];
    void* dst[9];
};

// ---------------------------------------------------------------------------
// K0 (merged prep + build + premult), 1024 threads/block, grid 9+B.
// Blocks 0..8: dtype probe; W1/W2 -> transposed bf16 images (stride 40/72);
//   others -> f32; block 0 writes flags[0] (x dtype, used for output dtype).
// Blocks 9..9+B-1: per-batch graph build (cnt in LDS, two passes) + fused
//   premult y = dis*x (local per-slice x-dtype probe); zeroes pooled/done.
// ---------------------------------------------------------------------------
__global__ __launch_bounds__(1024) void k_prep_build(
    PrepArgs pa, const int* __restrict__ eidx, const void* __restrict__ mask,
    const void* __restrict__ x, int* flags,
    int* __restrict__ n_arr, float* __restrict__ dis,
    unsigned char* __restrict__ degc, unsigned short* __restrict__ ssrc,
    int2* __restrict__ ovf, int* __restrict__ ovf_cnt,
    unsigned int* __restrict__ y_u, float* __restrict__ pooled,
    int* __restrict__ done) {
    const int bid = blockIdx.x;
    const int t = threadIdx.x;
    if (bid < 9) {
        int sz;
        switch (bid) {
            case 0: sz = B * N * F; break;
            case 1: sz = F * H; break;
            case 2: sz = H; break;
            case 3: sz = H * H; break;
            case 4: sz = H; break;
            case 5: sz = H * H; break;
            case 6: sz = H; break;
            case 7: sz = H * OUTD; break;
            default: sz = OUTD; break;
        }
        const int K = sz < 1024 ? sz : 1024;
        const unsigned short* p = (const unsigned short*)pa.src[bid];
        float s = 0.f;
        for (int i = t; i < K; i += 1024) s += fminf(fabsf(b2f(p[i])), 1e6f);
        __shared__ float s_w[16];
        __shared__ int isbf;
        for (int o = 32; o > 0; o >>= 1) s += __shfl_down(s, o);
        if ((t & 63) == 0) s_w[t >> 6] = s;
        __syncthreads();
        if (t == 0) {
            float a = 0.f;
            for (int i = 0; i < 16; i++) a += s_w[i];
            int f = (a < 100.0f * (float)K) ? 1 : 0;
            isbf = f;
            if (bid == 0) flags[0] = f;
        }
        __syncthreads();
        if (bid == 0) return;
        const int fl = isbf;
        auto rd = [&](int i) -> float {
            return fl ? b2f(((const unsigned short*)pa.src[bid])[i])
                      : ((const float*)pa.src[bid])[i];
        };
        if (bid == 1) {  // W1 -> W1T bf16 image, stride 40
            unsigned short* dst = (unsigned short*)pa.dst[bid];
            for (int i = t; i < F * H; i += 1024) {
                int k = i >> 6, n2 = i & 63;
                dst[n2 * 40 + k] = f2b(rd(i));
            }
        } else if (bid == 3) {  // W2 -> W2T bf16 image, stride 72
            unsigned short* dst = (unsigned short*)pa.dst[bid];
            for (int i = t; i < H * H; i += 1024) {
                int k = i >> 6, n2 = i & 63;
                dst[n2 * 72 + k] = f2b(rd(i));
            }
        } else {
            float* dst = (float*)pa.dst[bid];
            for (int i = t; i < sz; i += 1024) dst[i] = rd(i);
        }
        return;
    }
    // ---------------- build part ----------------
    __shared__ int s_cnt[N];
    __shared__ int s_w[16];
    __shared__ float s_wx[16];
    __shared__ int s_n;
    __shared__ int s_ovf;
    __shared__ int s_xbf;
    const int b = bid - 9;
    const int bN = b * N;
    const unsigned char* mb = (const unsigned char*)mask;
    int mode;
    if (mb[0] == 0x80 && mb[1] == 0x3F) mode = 2;        // bf16
    else if (mb[0] != 0 && mb[1] != 0) mode = 0;         // bytes
    else if (mb[0] != 0) mode = (mb[4] != 0) ? 1 : 4;    // int32 : int64
    else mode = 3;                                       // f32
    int cnt = 0;
    if (mode == 0) {
        const unsigned char* r = mb + (size_t)b * N;
        for (int i = t; i < N; i += 1024) cnt += (r[i] != 0);
    } else if (mode == 1 || mode == 3) {
        const unsigned int* r = (const unsigned int*)mask + (size_t)b * N;
        for (int i = t; i < N; i += 1024) cnt += (r[i] != 0);
    } else if (mode == 2) {
        const unsigned short* r = (const unsigned short*)mask + (size_t)b * N;
        for (int i = t; i < N; i += 1024) cnt += (r[i] != 0);
    } else {
        const unsigned long long* r = (const unsigned long long*)mask + (size_t)b * N;
        for (int i = t; i < N; i += 1024) cnt += (r[i] != 0ULL);
    }
    // local x-dtype probe on this batch's slice (same stats as global probe;
    // all-zero slices decode identically under both interpretations)
    float sx = fminf(fabsf(b2f(((const unsigned short*)x + (size_t)bN * F)[t])), 1e6f);
    for (int o = 32; o > 0; o >>= 1) {
        cnt += __shfl_down(cnt, o);
        sx += __shfl_down(sx, o);
    }
    if ((t & 63) == 0) { s_w[t >> 6] = cnt; s_wx[t >> 6] = sx; }
    for (int i = t; i < N; i += 1024) s_cnt[i] = 0;
    if (t == 0) s_ovf = 0;
    __syncthreads();
    if (t == 0) {
        int a = 0;
        float ax = 0.f;
        for (int i = 0; i < 16; i++) { a += s_w[i]; ax += s_wx[i]; }
        s_n = a > N ? N : a;
        s_xbf = (ax < 100.0f * 1024.0f) ? 1 : 0;
    }
    __syncthreads();
    const int n = s_n;
    const int4* es4 = (const int4*)(eidx + (size_t)b * 2 * E);
    const int4* ed4 = es4 + E / 4;
    for (int i = t; i < E / 4; i += 1024) {
        int4 s4 = es4[i], d4 = ed4[i];
        if ((unsigned)s4.x < (unsigned)n && (unsigned)d4.x < (unsigned)n) atomicAdd(&s_cnt[d4.x], 1);
        if ((unsigned)s4.y < (unsigned)n && (unsigned)d4.y < (unsigned)n) atomicAdd(&s_cnt[d4.y], 1);
        if ((unsigned)s4.z < (unsigned)n && (unsigned)d4.z < (unsigned)n) atomicAdd(&s_cnt[d4.z], 1);
        if ((unsigned)s4.w < (unsigned)n && (unsigned)d4.w < (unsigned)n) atomicAdd(&s_cnt[d4.w], 1);
    }
    __syncthreads();
    for (int v = t; v < N; v += 1024) {
        int c = s_cnt[v];
        dis[bN + v] = (v < n) ? rsqrtf((float)(c + 1)) : 0.0f;
        degc[bN + v] = (unsigned char)(c < CAP ? c : CAP);
        s_cnt[v] = 0;
    }
    __syncthreads();
    for (int i = t; i < E / 4; i += 1024) {
        int4 s4 = es4[i], d4 = ed4[i];
#define FILL1(SS, DD)                                                          \
        if ((unsigned)(SS) < (unsigned)n && (unsigned)(DD) < (unsigned)n) {    \
            int pos = atomicAdd(&s_cnt[DD], 1);                                \
            if (pos < CAP)                                                     \
                ssrc[((size_t)(bN + (DD))) * CAP + pos] = (unsigned short)(SS);\
            else {                                                             \
                int oi = atomicAdd(&s_ovf, 1);                                 \
                if (oi < E) ovf[(size_t)b * E + oi] = make_int2((DD), (SS));   \
            }                                                                  \
        }
        FILL1(s4.x, d4.x) FILL1(s4.y, d4.y) FILL1(s4.z, d4.z) FILL1(s4.w, d4.w)
#undef FILL1
    }
    __syncthreads();  // s_cnt now holds full deg again
    // fused premult: y[v] = dis[v] * x[v], packed bf16 pairs
    const int xbf = s_xbf;
    unsigned int* yb = y_u + (size_t)bN * (F / 2);
    for (int i = t; i < N * (F / 2); i += 1024) {
        int v = i >> 4;
        float dv = (v < n) ? rsqrtf((float)(s_cnt[v] + 1)) : 0.0f;
        float a, c;
        if (xbf) {
            unsigned int u = ((const unsigned int*)x)[(size_t)bN * (F / 2) + i];
            a = __uint_as_float(u << 16);
            c = __uint_as_float(u & 0xffff0000u);
        } else {
            float2 f = ((const float2*)x)[(size_t)bN * (F / 2) + i];
            a = f.x; c = f.y;
        }
        yb[i] = pack2(a * dv, c * dv);
    }
    if (t < H) pooled[b * H + t] = 0.0f;
    if (t == H) done[b] = 0;
    if (t == 0) { n_arr[b] = n; ovf_cnt[b] = s_ovf; }
}

// ---------------------------------------------------------------------------
// K1: layer-1 gather (dynamic wave-uniform bound; 4 edges/instruction,
// predicated) + MFMA GEMM1 + relu + dis-premult -> z (bf16). XCD swizzle.
// ---------------------------------------------------------------------------
__global__ __launch_bounds__(256) void k_agg_gemm1(
    const unsigned int* __restrict__ y_u, const float* __restrict__ dis,
    const unsigned char* __restrict__ degc, const unsigned short* __restrict__ ssrc,
    const int2* __restrict__ ovf, const int* __restrict__ ovf_cnt,
    const unsigned short* __restrict__ w1t, const float* __restrict__ b1f,
    unsigned short* __restrict__ zs) {
    __shared__ unsigned short s_e[64 * CAP];
    __shared__ unsigned char s_dg[64];
    __shared__ float s_dv[64];
    __shared__ float s_b1[64];
    __shared__ __align__(16) unsigned short s_w1t[64 * 40];
    __shared__ __align__(16) unsigned short s_a1[64 * 40];
    const int bid = blockIdx.x;
    const int b = (bid & 7) + ((bid >> 8) << 3);
    const int v0 = ((bid >> 3) & 31) * 64;
    const int t = threadIdx.x;
    const int bN = b * N;
    if (t < 128) ((int4*)s_e)[t] = ((const int4*)(ssrc + (size_t)(bN + v0) * CAP))[t];
    if (t >= 128 && t < 144)
        ((unsigned int*)s_dg)[t - 128] = ((const unsigned int*)(degc + bN + v0))[t - 128];
    if (t >= 192) s_dv[t - 192] = dis[bN + v0 + (t - 192)];
    if (t >= 144 && t < 208) s_b1[t - 144] = b1f[t - 144];
    for (int i = t; i < 320; i += 256) ((int4*)s_w1t)[i] = ((const int4*)w1t)[i];
    __syncthreads();
    const int lane = t & 63;
    const int w = t >> 6;
    const int quad = lane >> 4;
    const int f2 = lane & 15;
    const int oc = ovf_cnt[b];
    const unsigned int* yb = y_u + (size_t)bN * (F / 2);
    for (int k = 0; k < 16; k++) {
        const int nn = w * 16 + k;
        const int v = v0 + nn;
        const int dg = s_dg[nn];
        const unsigned short* ep = &s_e[nn * CAP];
        float ax = 0.f, ay = 0.f;
        for (int s0 = 0; s0 < dg; s0 += 4) {   // wave-uniform bound
            int slot = s0 + quad;
            int idx = ep[slot] & (N - 1);
            bool pred = slot < dg;
            unsigned int u = yb[(size_t)idx * (F / 2) + f2];
            float lo = __uint_as_float(u << 16);
            float hi = __uint_as_float(u & 0xffff0000u);
            ax += pred ? lo : 0.0f;
            ay += pred ? hi : 0.0f;
        }
        ax += __shfl_xor(ax, 16); ay += __shfl_xor(ay, 16);
        ax += __shfl_xor(ax, 32); ay += __shfl_xor(ay, 32);
        if (quad == 0) {
            unsigned int u = yb[(size_t)v * (F / 2) + f2];  // self (premultiplied)
            ax += __uint_as_float(u << 16);
            ay += __uint_as_float(u & 0xffff0000u);
            if (oc > 0) {  // deg>CAP spills; ~never taken
                const int2* ob = ovf + (size_t)b * E;
                for (int j = 0; j < oc; j++) {
                    int2 o = ob[j];
                    if (o.x == v) {
                        unsigned int uo = yb[(size_t)o.y * (F / 2) + f2];
                        ax += __uint_as_float(uo << 16);
                        ay += __uint_as_float(uo & 0xffff0000u);
                    }
                }
            }
            float dv = s_dv[nn];
            *(unsigned int*)&s_a1[nn * 40 + 2 * f2] = pack2(ax * dv, ay * dv);
        }
    }
    __syncthreads();
    // MFMA GEMM1: wave w -> rows m0..m0+15 of (a1 @ W1)
    const int m0 = w * 16;
    bf16x8 af = *(const bf16x8*)&s_a1[(m0 + f2) * 40 + quad * 8];
    float dvr[4];
#pragma unroll
    for (int r = 0; r < 4; r++) dvr[r] = s_dv[m0 + quad * 4 + r];
#pragma unroll
    for (int nt = 0; nt < 4; nt++) {
        bf16x8 bf = *(const bf16x8*)&s_w1t[(nt * 16 + f2) * 40 + quad * 8];
        f32x4 acc = {0.f, 0.f, 0.f, 0.f};
        acc = __builtin_amdgcn_mfma_f32_16x16x32_bf16(af, bf, acc, 0, 0, 0);
        float bb = s_b1[nt * 16 + f2];
#pragma unroll
        for (int r = 0; r < 4; r++) {
            int row = m0 + quad * 4 + r;
            float val = dvr[r] * fmaxf(acc[r] + bb, 0.0f);
            zs[(size_t)(bN + v0 + row) * H + nt * 16 + f2] = f2b(val);
        }
    }
}

// ---------------------------------------------------------------------------
// K2: layer-2 gather + MFMA GEMM2 + relu + pool + FUSED MLP head (last block
// per batch runs the head via threadfence-reduction pattern).
// ---------------------------------------------------------------------------
__global__ __launch_bounds__(256) void k_agg_gemm2_pool(
    const unsigned int* __restrict__ z_u, const float* __restrict__ dis,
    const unsigned char* __restrict__ degc, const unsigned short* __restrict__ ssrc,
    const int2* __restrict__ ovf, const int* __restrict__ ovf_cnt,
    const unsigned short* __restrict__ w2t, const float* __restrict__ b2f_,
    float* __restrict__ pooled, int* __restrict__ done,
    const int* __restrict__ n_arr,
    const float* __restrict__ aW1, const float* __restrict__ ab1,
    const float* __restrict__ aW2, const float* __restrict__ ab2,
    const int* __restrict__ flags, void* __restrict__ out) {
    __shared__ unsigned short s_e[64 * CAP];
    __shared__ unsigned char s_dg[64];
    __shared__ float s_dv[64];
    __shared__ float s_b2[64];
    __shared__ __align__(16) unsigned short s_w2t[64 * 72];
    __shared__ __align__(16) unsigned short s_a2[64 * 72];
    __shared__ float s_pool[4][64];
    __shared__ int s_last;
    __shared__ float s_p[64];
    __shared__ float s_hid[64];
    const int bid = blockIdx.x;
    const int b = (bid & 7) + ((bid >> 8) << 3);
    const int v0 = ((bid >> 3) & 31) * 64;
    const int t = threadIdx.x;
    const int bN = b * N;
    if (t < 128) ((int4*)s_e)[t] = ((const int4*)(ssrc + (size_t)(bN + v0) * CAP))[t];
    if (t >= 128 && t < 144)
        ((unsigned int*)s_dg)[t - 128] = ((const unsigned int*)(degc + bN + v0))[t - 128];
    if (t >= 192) s_dv[t - 192] = dis[bN + v0 + (t - 192)];
    if (t >= 144 && t < 208) s_b2[t - 144] = b2f_[t - 144];
    for (int i = t; i < 576; i += 256) ((int4*)s_w2t)[i] = ((const int4*)w2t)[i];
    __syncthreads();
    const int lane = t & 63;
    const int w = t >> 6;
    const int half = lane >> 5;
    const int f2h = lane & 31;
    const int quad = lane >> 4;
    const int f2 = lane & 15;
    const int oc = ovf_cnt[b];
    const unsigned int* zb = z_u + (size_t)bN * (H / 2);
    for (int k = 0; k < 16; k++) {
        const int nn = w * 16 + k;
        const int v = v0 + nn;
        const int dg = s_dg[nn];
        const unsigned short* ep = &s_e[nn * CAP];
        float ax = 0.f, ay = 0.f;
        for (int s0 = 0; s0 < dg; s0 += 2) {   // wave-uniform bound
            int slot = s0 + half;
            int idx = ep[slot] & (N - 1);
            bool pred = slot < dg;
            unsigned int u = zb[(size_t)idx * (H / 2) + f2h];
            float lo = __uint_as_float(u << 16);
            float hi = __uint_as_float(u & 0xffff0000u);
            ax += pred ? lo : 0.0f;
            ay += pred ? hi : 0.0f;
        }
        ax += __shfl_xor(ax, 32); ay += __shfl_xor(ay, 32);
        if (half == 0) {
            unsigned int u = zb[(size_t)v * (H / 2) + f2h];  // self
            ax += __uint_as_float(u << 16);
            ay += __uint_as_float(u & 0xffff0000u);
            if (oc > 0) {
                const int2* ob = ovf + (size_t)b * E;
                for (int j = 0; j < oc; j++) {
                    int2 o = ob[j];
                    if (o.x == v) {
                        unsigned int uo = zb[(size_t)o.y * (H / 2) + f2h];
                        ax += __uint_as_float(uo << 16);
                        ay += __uint_as_float(uo & 0xffff0000u);
                    }
                }
            }
            float dv = s_dv[nn];
            *(unsigned int*)&s_a2[nn * 72 + 2 * f2h] = pack2(ax * dv, ay * dv);
        }
    }
    __syncthreads();
    // MFMA GEMM2 + pool
    const int m0 = w * 16;
    bf16x8 af0 = *(const bf16x8*)&s_a2[(m0 + f2) * 72 + quad * 8];
    bf16x8 af1 = *(const bf16x8*)&s_a2[(m0 + f2) * 72 + 32 + quad * 8];
    float dvr[4];
#pragma unroll
    for (int r = 0; r < 4; r++) dvr[r] = s_dv[m0 + quad * 4 + r];
#pragma unroll
    for (int nt = 0; nt < 4; nt++) {
        bf16x8 bf0 = *(const bf16x8*)&s_w2t[(nt * 16 + f2) * 72 + quad * 8];
        bf16x8 bf1 = *(const bf16x8*)&s_w2t[(nt * 16 + f2) * 72 + 32 + quad * 8];
        f32x4 acc = {0.f, 0.f, 0.f, 0.f};
        acc = __builtin_amdgcn_mfma_f32_16x16x32_bf16(af0, bf0, acc, 0, 0, 0);
        acc = __builtin_amdgcn_mfma_f32_16x16x32_bf16(af1, bf1, acc, 0, 0, 0);
        float bb = s_b2[nt * 16 + f2];
        float ps = 0.f;
#pragma unroll
        for (int r = 0; r < 4; r++)
            ps += (dvr[r] > 0.0f) ? fmaxf(acc[r] + bb, 0.0f) : 0.0f;
        ps += __shfl_xor(ps, 16);
        ps += __shfl_xor(ps, 32);
        if (quad == 0) s_pool[w][nt * 16 + f2] = ps;
    }
    __syncthreads();
    if (t < H)
        atomicAdd(&pooled[b * H + t],
                  s_pool[0][t] + s_pool[1][t] + s_pool[2][t] + s_pool[3][t]);
    // ---- fused MLP head: last block of this batch's 32 runs it ----
    __threadfence();
    __syncthreads();
    if (t == 0) {
        int prev = atomicAdd(&done[b], 1);
        s_last = (prev == 31);
    }
    __syncthreads();
    if (!s_last) return;
    __threadfence();
    int n = n_arr[b];
    if (n < 1) n = 1;
    if (t < 64) s_p[t] = atomicAdd(&pooled[b * H + t], 0.0f) / (float)n;
    __syncthreads();
    if (t < 64) {
        float acc = ab1[t];
        for (int j = 0; j < 64; j++) acc += s_p[j] * aW1[j * 64 + t];
        s_hid[t] = fmaxf(acc, 0.0f);
    }
    __syncthreads();
    if (t < 16) {
        float a2 = ab2[t];
        for (int j = 0; j < 64; j++) a2 += s_hid[j] * aW2[j * 16 + t];
        if (flags[0]) ((unsigned short*)out)[b * OUTD + t] = f2b(a2);
        else          ((float*)out)[b * OUTD + t] = a2;
    }
}

// ---------------------------------------------------------------------------
extern "C" void kernel_launch(void* const* d_in, const int* in_sizes, int n_in,
                              void* d_out, int out_size, void* d_ws, size_t ws_size,
                              hipStream_t stream) {
    const void* x    = d_in[0];
    const int*  eidx = (const int*)d_in[1];
    const void* mask = d_in[2];

    char* ws = (char*)d_ws;
    size_t off = 0;
    auto alloc = [&](size_t bytes) -> void* {
        void* p = ws + off;
        off += (bytes + 255) & ~(size_t)255;
        return p;
    };
    int*   flags   = (int*)alloc(16 * sizeof(int));
    unsigned short* w1t = (unsigned short*)alloc(64 * 40 * 2);
    unsigned short* w2t = (unsigned short*)alloc(64 * 72 * 2);
    float* b1f     = (float*)alloc(H * sizeof(float));
    float* b2f_    = (float*)alloc(H * sizeof(float));
    float* aW1f    = (float*)alloc(H * H * sizeof(float));
    float* ab1f    = (float*)alloc(H * sizeof(float));
    float* aW2f    = (float*)alloc(H * OUTD * sizeof(float));
    float* ab2f    = (float*)alloc(OUTD * sizeof(float));
    int*   n_arr   = (int*)alloc(B * sizeof(int));
    float* dis     = (float*)alloc((size_t)B * N * sizeof(float));
    unsigned char*  degc = (unsigned char*)alloc((size_t)B * N);
    unsigned short* ssrc = (unsigned short*)alloc((size_t)B * N * CAP * 2);
    int2*  ovf     = (int2*)alloc((size_t)B * E * sizeof(int2));
    int*   ovf_cnt = (int*)alloc(B * sizeof(int));
    float* pooled  = (float*)alloc((size_t)B * H * sizeof(float));
    int*   done    = (int*)alloc(B * sizeof(int));
    unsigned int* y_u = (unsigned int*)alloc((size_t)B * N * (F / 2) * 4);
    unsigned int* z_u = (unsigned int*)alloc((size_t)B * N * (H / 2) * 4);

    PrepArgs pa;
    pa.src[0] = x;        pa.dst[0] = pooled;  // dst[0] unused
    pa.src[1] = d_in[3];  pa.dst[1] = w1t;
    pa.src[2] = d_in[4];  pa.dst[2] = b1f;
    pa.src[3] = d_in[5];  pa.dst[3] = w2t;
    pa.src[4] = d_in[6];  pa.dst[4] = b2f_;
    pa.src[5] = d_in[7];  pa.dst[5] = aW1f;
    pa.src[6] = d_in[8];  pa.dst[6] = ab1f;
    pa.src[7] = d_in[9];  pa.dst[7] = aW2f;
    pa.src[8] = d_in[10]; pa.dst[8] = ab2f;

    k_prep_build<<<9 + B, 1024, 0, stream>>>(pa, eidx, mask, x, flags, n_arr,
                                             dis, degc, ssrc, ovf, ovf_cnt,
                                             y_u, pooled, done);
    // a1 = dis*(y[v]+sum y[s]); z = dis * relu(a1@W1 + b1)   [MFMA]
    k_agg_gemm1<<<B * 32, 256, 0, stream>>>(y_u, dis, degc, ssrc, ovf, ovf_cnt,
                                            w1t, b1f, (unsigned short*)z_u);
    // a2 = dis*(z[v]+sum z[s]); h2 = relu(a2@W2+b2); pool; last block: MLP
    k_agg_gemm2_pool<<<B * 32, 256, 0, stream>>>(z_u, dis, degc, ssrc, ovf,
                                                 ovf_cnt, w2t, b2f_, pooled,
                                                 done, n_arr, aW1f, ab1f, aW2f,
                                                 ab2f, flags, d_out);
}

// Round 13
// 255.881 us; speedup vs baseline: 2.1816x; 2.1816x over previous
//
#include <hip/hip_runtime.h>
#include <hip/hip_bf16.h>

#define B 128
#define N 2048
#define E 16384
#define F 32
#define H 64
#define OUTD 16
#define CAP 16

typedef __attribute__((ext_vector_type(8))) short bf16x8;
typedef __attribute__((ext_vector_type(4))) float f32x4;

__device__ __forceinline__ float b2f(unsigned short u) {
    return __uint_as_float(((unsigned int)u) << 16);
}
__device__ __forceinline__ unsigned short f2b(float f) {
    unsigned int x = __float_as_uint(f);
    unsigned int r = (x + 0x7FFFu + ((x >> 16) & 1u)) >> 16;  // RNE, finite
    return (unsigned short)r;
}
__device__ __forceinline__ unsigned int pack2(float a, float b) {
    return (unsigned int)f2b(a) | ((unsigned int)f2b(b) << 16);
}

struct PrepArgs {
    const void* src[9];
    void* dst[9];
};

// ---------------------------------------------------------------------------
// K0 (merged prep + build + premult), 1024 threads/block, grid 9+B.
// Blocks 0..8: dtype probe; W1/W2 -> transposed bf16 images (stride 40/72);
//   others -> f32; block 0 writes flags[0] (x dtype -> output dtype).
// Blocks 9..9+B-1: per-batch graph build (cnt in LDS, two passes) + fused
//   premult y = dis*x (local per-slice x-dtype probe); zeroes pooled.
// ---------------------------------------------------------------------------
__global__ __launch_bounds__(1024) void k_prep_build(
    PrepArgs pa, const int* __restrict__ eidx, const void* __restrict__ mask,
    const void* __restrict__ x, int* flags,
    int* __restrict__ n_arr, float* __restrict__ dis,
    unsigned char* __restrict__ degc, unsigned short* __restrict__ ssrc,
    int2* __restrict__ ovf, int* __restrict__ ovf_cnt,
    unsigned int* __restrict__ y_u, float* __restrict__ pooled) {
    const int bid = blockIdx.x;
    const int t = threadIdx.x;
    if (bid < 9) {
        int sz;
        switch (bid) {
            case 0: sz = B * N * F; break;
            case 1: sz = F * H; break;
            case 2: sz = H; break;
            case 3: sz = H * H; break;
            case 4: sz = H; break;
            case 5: sz = H * H; break;
            case 6: sz = H; break;
            case 7: sz = H * OUTD; break;
            default: sz = OUTD; break;
        }
        const int K = sz < 1024 ? sz : 1024;
        const unsigned short* p = (const unsigned short*)pa.src[bid];
        float s = 0.f;
        for (int i = t; i < K; i += 1024) s += fminf(fabsf(b2f(p[i])), 1e6f);
        __shared__ float s_w[16];
        __shared__ int isbf;
        for (int o = 32; o > 0; o >>= 1) s += __shfl_down(s, o);
        if ((t & 63) == 0) s_w[t >> 6] = s;
        __syncthreads();
        if (t == 0) {
            float a = 0.f;
            for (int i = 0; i < 16; i++) a += s_w[i];
            int f = (a < 100.0f * (float)K) ? 1 : 0;
            isbf = f;
            if (bid == 0) flags[0] = f;
        }
        __syncthreads();
        if (bid == 0) return;
        const int fl = isbf;
        auto rd = [&](int i) -> float {
            return fl ? b2f(((const unsigned short*)pa.src[bid])[i])
                      : ((const float*)pa.src[bid])[i];
        };
        if (bid == 1) {  // W1 -> W1T bf16 image, stride 40
            unsigned short* dst = (unsigned short*)pa.dst[bid];
            for (int i = t; i < F * H; i += 1024) {
                int k = i >> 6, n2 = i & 63;
                dst[n2 * 40 + k] = f2b(rd(i));
            }
        } else if (bid == 3) {  // W2 -> W2T bf16 image, stride 72
            unsigned short* dst = (unsigned short*)pa.dst[bid];
            for (int i = t; i < H * H; i += 1024) {
                int k = i >> 6, n2 = i & 63;
                dst[n2 * 72 + k] = f2b(rd(i));
            }
        } else {
            float* dst = (float*)pa.dst[bid];
            for (int i = t; i < sz; i += 1024) dst[i] = rd(i);
        }
        return;
    }
    // ---------------- build part ----------------
    __shared__ int s_cnt[N];
    __shared__ int s_w[16];
    __shared__ float s_wx[16];
    __shared__ int s_n;
    __shared__ int s_ovf;
    __shared__ int s_xbf;
    const int b = bid - 9;
    const int bN = b * N;
    const unsigned char* mb = (const unsigned char*)mask;
    int mode;
    if (mb[0] == 0x80 && mb[1] == 0x3F) mode = 2;        // bf16
    else if (mb[0] != 0 && mb[1] != 0) mode = 0;         // bytes
    else if (mb[0] != 0) mode = (mb[4] != 0) ? 1 : 4;    // int32 : int64
    else mode = 3;                                       // f32
    int cnt = 0;
    if (mode == 0) {
        const unsigned char* r = mb + (size_t)b * N;
        for (int i = t; i < N; i += 1024) cnt += (r[i] != 0);
    } else if (mode == 1 || mode == 3) {
        const unsigned int* r = (const unsigned int*)mask + (size_t)b * N;
        for (int i = t; i < N; i += 1024) cnt += (r[i] != 0);
    } else if (mode == 2) {
        const unsigned short* r = (const unsigned short*)mask + (size_t)b * N;
        for (int i = t; i < N; i += 1024) cnt += (r[i] != 0);
    } else {
        const unsigned long long* r = (const unsigned long long*)mask + (size_t)b * N;
        for (int i = t; i < N; i += 1024) cnt += (r[i] != 0ULL);
    }
    // local x-dtype probe on this batch's slice (bf16 decode of f32 bits
    // yields huge magnitudes; all-zero slices decode identically either way)
    float sx = fminf(fabsf(b2f(((const unsigned short*)x + (size_t)bN * F)[t])), 1e6f);
    for (int o = 32; o > 0; o >>= 1) {
        cnt += __shfl_down(cnt, o);
        sx += __shfl_down(sx, o);
    }
    if ((t & 63) == 0) { s_w[t >> 6] = cnt; s_wx[t >> 6] = sx; }
    for (int i = t; i < N; i += 1024) s_cnt[i] = 0;
    if (t == 0) s_ovf = 0;
    __syncthreads();
    if (t == 0) {
        int a = 0;
        float ax = 0.f;
        for (int i = 0; i < 16; i++) { a += s_w[i]; ax += s_wx[i]; }
        s_n = a > N ? N : a;
        s_xbf = (ax < 100.0f * 1024.0f) ? 1 : 0;
    }
    __syncthreads();
    const int n = s_n;
    const int4* es4 = (const int4*)(eidx + (size_t)b * 2 * E);
    const int4* ed4 = es4 + E / 4;
    for (int i = t; i < E / 4; i += 1024) {
        int4 s4 = es4[i], d4 = ed4[i];
        if ((unsigned)s4.x < (unsigned)n && (unsigned)d4.x < (unsigned)n) atomicAdd(&s_cnt[d4.x], 1);
        if ((unsigned)s4.y < (unsigned)n && (unsigned)d4.y < (unsigned)n) atomicAdd(&s_cnt[d4.y], 1);
        if ((unsigned)s4.z < (unsigned)n && (unsigned)d4.z < (unsigned)n) atomicAdd(&s_cnt[d4.z], 1);
        if ((unsigned)s4.w < (unsigned)n && (unsigned)d4.w < (unsigned)n) atomicAdd(&s_cnt[d4.w], 1);
    }
    __syncthreads();
    for (int v = t; v < N; v += 1024) {
        int c = s_cnt[v];
        dis[bN + v] = (v < n) ? rsqrtf((float)(c + 1)) : 0.0f;
        degc[bN + v] = (unsigned char)(c < CAP ? c : CAP);
        s_cnt[v] = 0;
    }
    __syncthreads();
    for (int i = t; i < E / 4; i += 1024) {
        int4 s4 = es4[i], d4 = ed4[i];
#define FILL1(SS, DD)                                                          \
        if ((unsigned)(SS) < (unsigned)n && (unsigned)(DD) < (unsigned)n) {    \
            int pos = atomicAdd(&s_cnt[DD], 1);                                \
            if (pos < CAP)                                                     \
                ssrc[((size_t)(bN + (DD))) * CAP + pos] = (unsigned short)(SS);\
            else {                                                             \
                int oi = atomicAdd(&s_ovf, 1);                                 \
                if (oi < E) ovf[(size_t)b * E + oi] = make_int2((DD), (SS));   \
            }                                                                  \
        }
        FILL1(s4.x, d4.x) FILL1(s4.y, d4.y) FILL1(s4.z, d4.z) FILL1(s4.w, d4.w)
#undef FILL1
    }
    __syncthreads();  // s_cnt holds full deg again
    // fused premult: y[v] = dis[v] * x[v], packed bf16 pairs
    const int xbf = s_xbf;
    unsigned int* yb = y_u + (size_t)bN * (F / 2);
    for (int i = t; i < N * (F / 2); i += 1024) {
        int v = i >> 4;
        float dv = (v < n) ? rsqrtf((float)(s_cnt[v] + 1)) : 0.0f;
        float a, c;
        if (xbf) {
            unsigned int u = ((const unsigned int*)x)[(size_t)bN * (F / 2) + i];
            a = __uint_as_float(u << 16);
            c = __uint_as_float(u & 0xffff0000u);
        } else {
            float2 f = ((const float2*)x)[(size_t)bN * (F / 2) + i];
            a = f.x; c = f.y;
        }
        yb[i] = pack2(a * dv, c * dv);
    }
    if (t < H) pooled[b * H + t] = 0.0f;
    if (t == 0) { n_arr[b] = n; ovf_cnt[b] = s_ovf; }
}

// ---------------------------------------------------------------------------
// K1: layer-1 gather (dynamic wave-uniform bound; 4 edges/instruction,
// predicated) + MFMA GEMM1 + relu + dis-premult -> z (bf16). XCD swizzle.
// ---------------------------------------------------------------------------
__global__ __launch_bounds__(256) void k_agg_gemm1(
    const unsigned int* __restrict__ y_u, const float* __restrict__ dis,
    const unsigned char* __restrict__ degc, const unsigned short* __restrict__ ssrc,
    const int2* __restrict__ ovf, const int* __restrict__ ovf_cnt,
    const unsigned short* __restrict__ w1t, const float* __restrict__ b1f,
    unsigned short* __restrict__ zs) {
    __shared__ unsigned short s_e[64 * CAP];
    __shared__ unsigned char s_dg[64];
    __shared__ float s_dv[64];
    __shared__ float s_b1[64];
    __shared__ __align__(16) unsigned short s_w1t[64 * 40];
    __shared__ __align__(16) unsigned short s_a1[64 * 40];
    const int bid = blockIdx.x;
    const int b = (bid & 7) + ((bid >> 8) << 3);
    const int v0 = ((bid >> 3) & 31) * 64;
    const int t = threadIdx.x;
    const int bN = b * N;
    if (t < 128) ((int4*)s_e)[t] = ((const int4*)(ssrc + (size_t)(bN + v0) * CAP))[t];
    if (t >= 128 && t < 144)
        ((unsigned int*)s_dg)[t - 128] = ((const unsigned int*)(degc + bN + v0))[t - 128];
    if (t >= 192) s_dv[t - 192] = dis[bN + v0 + (t - 192)];
    if (t >= 144 && t < 208) s_b1[t - 144] = b1f[t - 144];
    for (int i = t; i < 320; i += 256) ((int4*)s_w1t)[i] = ((const int4*)w1t)[i];
    __syncthreads();
    const int lane = t & 63;
    const int w = t >> 6;
    const int quad = lane >> 4;
    const int f2 = lane & 15;
    const int oc = ovf_cnt[b];
    const unsigned int* yb = y_u + (size_t)bN * (F / 2);
    for (int k = 0; k < 16; k++) {
        const int nn = w * 16 + k;
        const int v = v0 + nn;
        const int dg = s_dg[nn];
        const unsigned short* ep = &s_e[nn * CAP];
        float ax = 0.f, ay = 0.f;
        for (int s0 = 0; s0 < dg; s0 += 4) {   // wave-uniform bound
            int slot = s0 + quad;
            int idx = ep[slot] & (N - 1);
            bool pred = slot < dg;
            unsigned int u = yb[(size_t)idx * (F / 2) + f2];
            float lo = __uint_as_float(u << 16);
            float hi = __uint_as_float(u & 0xffff0000u);
            ax += pred ? lo : 0.0f;
            ay += pred ? hi : 0.0f;
        }
        ax += __shfl_xor(ax, 16); ay += __shfl_xor(ay, 16);
        ax += __shfl_xor(ax, 32); ay += __shfl_xor(ay, 32);
        if (quad == 0) {
            unsigned int u = yb[(size_t)v * (F / 2) + f2];  // self (premultiplied)
            ax += __uint_as_float(u << 16);
            ay += __uint_as_float(u & 0xffff0000u);
            if (oc > 0) {  // deg>CAP spills; ~never taken
                const int2* ob = ovf + (size_t)b * E;
                for (int j = 0; j < oc; j++) {
                    int2 o = ob[j];
                    if (o.x == v) {
                        unsigned int uo = yb[(size_t)o.y * (F / 2) + f2];
                        ax += __uint_as_float(uo << 16);
                        ay += __uint_as_float(uo & 0xffff0000u);
                    }
                }
            }
            float dv = s_dv[nn];
            *(unsigned int*)&s_a1[nn * 40 + 2 * f2] = pack2(ax * dv, ay * dv);
        }
    }
    __syncthreads();
    // MFMA GEMM1: wave w -> rows m0..m0+15 of (a1 @ W1)
    const int m0 = w * 16;
    bf16x8 af = *(const bf16x8*)&s_a1[(m0 + f2) * 40 + quad * 8];
    float dvr[4];
#pragma unroll
    for (int r = 0; r < 4; r++) dvr[r] = s_dv[m0 + quad * 4 + r];
#pragma unroll
    for (int nt = 0; nt < 4; nt++) {
        bf16x8 bf = *(const bf16x8*)&s_w1t[(nt * 16 + f2) * 40 + quad * 8];
        f32x4 acc = {0.f, 0.f, 0.f, 0.f};
        acc = __builtin_amdgcn_mfma_f32_16x16x32_bf16(af, bf, acc, 0, 0, 0);
        float bb = s_b1[nt * 16 + f2];
#pragma unroll
        for (int r = 0; r < 4; r++) {
            int row = m0 + quad * 4 + r;
            float val = dvr[r] * fmaxf(acc[r] + bb, 0.0f);
            zs[(size_t)(bN + v0 + row) * H + nt * 16 + f2] = f2b(val);
        }
    }
}

// ---------------------------------------------------------------------------
// K2: layer-2 gather (dynamic bound; 2 edges/instruction, predicated) +
// MFMA GEMM2 + relu + pool. h2 never stored. (No fence/tail — r12 lesson.)
// ---------------------------------------------------------------------------
__global__ __launch_bounds__(256) void k_agg_gemm2_pool(
    const unsigned int* __restrict__ z_u, const float* __restrict__ dis,
    const unsigned char* __restrict__ degc, const unsigned short* __restrict__ ssrc,
    const int2* __restrict__ ovf, const int* __restrict__ ovf_cnt,
    const unsigned short* __restrict__ w2t, const float* __restrict__ b2f_,
    float* __restrict__ pooled) {
    __shared__ unsigned short s_e[64 * CAP];
    __shared__ unsigned char s_dg[64];
    __shared__ float s_dv[64];
    __shared__ float s_b2[64];
    __shared__ __align__(16) unsigned short s_w2t[64 * 72];
    __shared__ __align__(16) unsigned short s_a2[64 * 72];
    __shared__ float s_pool[4][64];
    const int bid = blockIdx.x;
    const int b = (bid & 7) + ((bid >> 8) << 3);
    const int v0 = ((bid >> 3) & 31) * 64;
    const int t = threadIdx.x;
    const int bN = b * N;
    if (t < 128) ((int4*)s_e)[t] = ((const int4*)(ssrc + (size_t)(bN + v0) * CAP))[t];
    if (t >= 128 && t < 144)
        ((unsigned int*)s_dg)[t - 128] = ((const unsigned int*)(degc + bN + v0))[t - 128];
    if (t >= 192) s_dv[t - 192] = dis[bN + v0 + (t - 192)];
    if (t >= 144 && t < 208) s_b2[t - 144] = b2f_[t - 144];
    for (int i = t; i < 576; i += 256) ((int4*)s_w2t)[i] = ((const int4*)w2t)[i];
    __syncthreads();
    const int lane = t & 63;
    const int w = t >> 6;
    const int half = lane >> 5;
    const int f2h = lane & 31;
    const int quad = lane >> 4;
    const int f2 = lane & 15;
    const int oc = ovf_cnt[b];
    const unsigned int* zb = z_u + (size_t)bN * (H / 2);
    for (int k = 0; k < 16; k++) {
        const int nn = w * 16 + k;
        const int v = v0 + nn;
        const int dg = s_dg[nn];
        const unsigned short* ep = &s_e[nn * CAP];
        float ax = 0.f, ay = 0.f;
        for (int s0 = 0; s0 < dg; s0 += 2) {   // wave-uniform bound
            int slot = s0 + half;
            int idx = ep[slot] & (N - 1);
            bool pred = slot < dg;
            unsigned int u = zb[(size_t)idx * (H / 2) + f2h];
            float lo = __uint_as_float(u << 16);
            float hi = __uint_as_float(u & 0xffff0000u);
            ax += pred ? lo : 0.0f;
            ay += pred ? hi : 0.0f;
        }
        ax += __shfl_xor(ax, 32); ay += __shfl_xor(ay, 32);
        if (half == 0) {
            unsigned int u = zb[(size_t)v * (H / 2) + f2h];  // self
            ax += __uint_as_float(u << 16);
            ay += __uint_as_float(u & 0xffff0000u);
            if (oc > 0) {
                const int2* ob = ovf + (size_t)b * E;
                for (int j = 0; j < oc; j++) {
                    int2 o = ob[j];
                    if (o.x == v) {
                        unsigned int uo = zb[(size_t)o.y * (H / 2) + f2h];
                        ax += __uint_as_float(uo << 16);
                        ay += __uint_as_float(uo & 0xffff0000u);
                    }
                }
            }
            float dv = s_dv[nn];
            *(unsigned int*)&s_a2[nn * 72 + 2 * f2h] = pack2(ax * dv, ay * dv);
        }
    }
    __syncthreads();
    // MFMA GEMM2 + pool
    const int m0 = w * 16;
    bf16x8 af0 = *(const bf16x8*)&s_a2[(m0 + f2) * 72 + quad * 8];
    bf16x8 af1 = *(const bf16x8*)&s_a2[(m0 + f2) * 72 + 32 + quad * 8];
    float dvr[4];
#pragma unroll
    for (int r = 0; r < 4; r++) dvr[r] = s_dv[m0 + quad * 4 + r];
#pragma unroll
    for (int nt = 0; nt < 4; nt++) {
        bf16x8 bf0 = *(const bf16x8*)&s_w2t[(nt * 16 + f2) * 72 + quad * 8];
        bf16x8 bf1 = *(const bf16x8*)&s_w2t[(nt * 16 + f2) * 72 + 32 + quad * 8];
        f32x4 acc = {0.f, 0.f, 0.f, 0.f};
        acc = __builtin_amdgcn_mfma_f32_16x16x32_bf16(af0, bf0, acc, 0, 0, 0);
        acc = __builtin_amdgcn_mfma_f32_16x16x32_bf16(af1, bf1, acc, 0, 0, 0);
        float bb = s_b2[nt * 16 + f2];
        float ps = 0.f;
#pragma unroll
        for (int r = 0; r < 4; r++)
            ps += (dvr[r] > 0.0f) ? fmaxf(acc[r] + bb, 0.0f) : 0.0f;
        ps += __shfl_xor(ps, 16);
        ps += __shfl_xor(ps, 32);
        if (quad == 0) s_pool[w][nt * 16 + f2] = ps;
    }
    __syncthreads();
    if (t < H)
        atomicAdd(&pooled[b * H + t],
                  s_pool[0][t] + s_pool[1][t] + s_pool[2][t] + s_pool[3][t]);
}

// ---------------------------------------------------------------------------
// K3: MLP head, one wave per batch.
// ---------------------------------------------------------------------------
__global__ __launch_bounds__(64) void k_mlp(
    const float* __restrict__ pooled, const int* __restrict__ n_arr,
    const float* __restrict__ aW1, const float* __restrict__ ab1,
    const float* __restrict__ aW2, const float* __restrict__ ab2,
    const int* __restrict__ flags, void* __restrict__ out) {
    const int b = blockIdx.x;
    const int t = threadIdx.x;
    __shared__ float p[64];
    __shared__ float hid[64];
    int n = n_arr[b];
    if (n < 1) n = 1;
    p[t] = pooled[b * H + t] / (float)n;
    __syncthreads();
    float acc = ab1[t];
    for (int j = 0; j < 64; j++) acc += p[j] * aW1[j * 64 + t];
    hid[t] = fmaxf(acc, 0.0f);
    __syncthreads();
    if (t < 16) {
        float a2 = ab2[t];
        for (int j = 0; j < 64; j++) a2 += hid[j] * aW2[j * 16 + t];
        if (flags[0]) ((unsigned short*)out)[b * OUTD + t] = f2b(a2);
        else          ((float*)out)[b * OUTD + t] = a2;
    }
}

// ---------------------------------------------------------------------------
extern "C" void kernel_launch(void* const* d_in, const int* in_sizes, int n_in,
                              void* d_out, int out_size, void* d_ws, size_t ws_size,
                              hipStream_t stream) {
    const void* x    = d_in[0];
    const int*  eidx = (const int*)d_in[1];
    const void* mask = d_in[2];

    char* ws = (char*)d_ws;
    size_t off = 0;
    auto alloc = [&](size_t bytes) -> void* {
        void* p = ws + off;
        off += (bytes + 255) & ~(size_t)255;
        return p;
    };
    int*   flags   = (int*)alloc(16 * sizeof(int));
    unsigned short* w1t = (unsigned short*)alloc(64 * 40 * 2);
    unsigned short* w2t = (unsigned short*)alloc(64 * 72 * 2);
    float* b1f     = (float*)alloc(H * sizeof(float));
    float* b2f_    = (float*)alloc(H * sizeof(float));
    float* aW1f    = (float*)alloc(H * H * sizeof(float));
    float* ab1f    = (float*)alloc(H * sizeof(float));
    float* aW2f    = (float*)alloc(H * OUTD * sizeof(float));
    float* ab2f    = (float*)alloc(OUTD * sizeof(float));
    int*   n_arr   = (int*)alloc(B * sizeof(int));
    float* dis     = (float*)alloc((size_t)B * N * sizeof(float));
    unsigned char*  degc = (unsigned char*)alloc((size_t)B * N);
    unsigned short* ssrc = (unsigned short*)alloc((size_t)B * N * CAP * 2);
    int2*  ovf     = (int2*)alloc((size_t)B * E * sizeof(int2));
    int*   ovf_cnt = (int*)alloc(B * sizeof(int));
    float* pooled  = (float*)alloc((size_t)B * H * sizeof(float));
    unsigned int* y_u = (unsigned int*)alloc((size_t)B * N * (F / 2) * 4);
    unsigned int* z_u = (unsigned int*)alloc((size_t)B * N * (H / 2) * 4);

    PrepArgs pa;
    pa.src[0] = x;        pa.dst[0] = pooled;  // dst[0] unused
    pa.src[1] = d_in[3];  pa.dst[1] = w1t;
    pa.src[2] = d_in[4];  pa.dst[2] = b1f;
    pa.src[3] = d_in[5];  pa.dst[3] = w2t;
    pa.src[4] = d_in[6];  pa.dst[4] = b2f_;
    pa.src[5] = d_in[7];  pa.dst[5] = aW1f;
    pa.src[6] = d_in[8];  pa.dst[6] = ab1f;
    pa.src[7] = d_in[9];  pa.dst[7] = aW2f;
    pa.src[8] = d_in[10]; pa.dst[8] = ab2f;

    k_prep_build<<<9 + B, 1024, 0, stream>>>(pa, eidx, mask, x, flags, n_arr,
                                             dis, degc, ssrc, ovf, ovf_cnt,
                                             y_u, pooled);
    // a1 = dis*(y[v]+sum y[s]); z = dis * relu(a1@W1 + b1)   [MFMA]
    k_agg_gemm1<<<B * 32, 256, 0, stream>>>(y_u, dis, degc, ssrc, ovf, ovf_cnt,
                                            w1t, b1f, (unsigned short*)z_u);
    // a2 = dis*(z[v]+sum z[s]); h2 = relu(a2@W2 + b2); pool  [MFMA]
    k_agg_gemm2_pool<<<B * 32, 256, 0, stream>>>(z_u, dis, degc, ssrc, ovf,
                                                 ovf_cnt, w2t, b2f_, pooled);
    // Head
    k_mlp<<<B, 64, 0, stream>>>(pooled, n_arr, aW1f, ab1f, aW2f, ab2f, flags, d_out);
}

// Round 14
// 225.808 us; speedup vs baseline: 2.4722x; 1.1332x over previous
//
#include <hip/hip_runtime.h>
#include <hip/hip_bf16.h>

#define B 128
#define N 2048
#define E 16384
#define F 32
#define H 64
#define OUTD 16
#define CAP 16

typedef __attribute__((ext_vector_type(8))) short bf16x8;
typedef __attribute__((ext_vector_type(4))) float f32x4;

__device__ __forceinline__ float b2f(unsigned short u) {
    return __uint_as_float(((unsigned int)u) << 16);
}
__device__ __forceinline__ unsigned short f2b(float f) {
    unsigned int x = __float_as_uint(f);
    unsigned int r = (x + 0x7FFFu + ((x >> 16) & 1u)) >> 16;  // RNE, finite
    return (unsigned short)r;
}
__device__ __forceinline__ unsigned int pack2(float a, float b) {
    return (unsigned int)f2b(a) | ((unsigned int)f2b(b) << 16);
}

struct PrepArgs {
    const void* src[9];
    void* dst[9];
};

// ---------------------------------------------------------------------------
// K0: prep (9 blocks). Dtype probe; W1/W2 -> transposed bf16 images
// (stride 40/72 ushorts) for flat int4 staging; others -> f32.
// ---------------------------------------------------------------------------
__global__ __launch_bounds__(256) void k_prep(PrepArgs pa, int* flags) {
    const int bid = blockIdx.x;
    const int t = threadIdx.x;
    int sz;
    switch (bid) {
        case 0: sz = B * N * F; break;
        case 1: sz = F * H; break;
        case 2: sz = H; break;
        case 3: sz = H * H; break;
        case 4: sz = H; break;
        case 5: sz = H * H; break;
        case 6: sz = H; break;
        case 7: sz = H * OUTD; break;
        default: sz = OUTD; break;
    }
    const int K = sz < 1024 ? sz : 1024;
    const unsigned short* p = (const unsigned short*)pa.src[bid];
    float s = 0.f;
    for (int i = t; i < K; i += 256) s += fminf(fabsf(b2f(p[i])), 1e6f);
    __shared__ float red[256];
    __shared__ int isbf;
    red[t] = s;
    __syncthreads();
    for (int st = 128; st > 0; st >>= 1) {
        if (t < st) red[t] += red[t + st];
        __syncthreads();
    }
    if (t == 0) {
        int f = (red[0] < 100.0f * (float)K) ? 1 : 0;
        isbf = f;
        if (bid == 0) flags[0] = f;
    }
    __syncthreads();
    if (bid == 0) return;
    const int fl = isbf;
    auto rd = [&](int i) -> float {
        return fl ? b2f(((const unsigned short*)pa.src[bid])[i])
                  : ((const float*)pa.src[bid])[i];
    };
    if (bid == 1) {  // W1 (32x64) -> W1T bf16 image, stride 40
        unsigned short* dst = (unsigned short*)pa.dst[bid];
        for (int i = t; i < F * H; i += 256) {
            int k = i >> 6, n2 = i & 63;
            dst[n2 * 40 + k] = f2b(rd(i));
        }
    } else if (bid == 3) {  // W2 (64x64) -> W2T bf16 image, stride 72
        unsigned short* dst = (unsigned short*)pa.dst[bid];
        for (int i = t; i < H * H; i += 256) {
            int k = i >> 6, n2 = i & 63;
            dst[n2 * 72 + k] = f2b(rd(i));
        }
    } else {
        float* dst = (float*)pa.dst[bid];
        for (int i = t; i < sz; i += 256) dst[i] = rd(i);
    }
}

// ---------------------------------------------------------------------------
// K1: graph build. One block of 1024 threads per batch. cnt in LDS; two
// passes. Emits n_arr, dis, degc, ssrc (ushort CSR), overflow; zeroes pooled.
// ---------------------------------------------------------------------------
__global__ __launch_bounds__(1024) void k_build(
    const int* __restrict__ eidx, const void* __restrict__ mask,
    int* __restrict__ n_arr, float* __restrict__ dis,
    unsigned char* __restrict__ degc, unsigned short* __restrict__ ssrc,
    int2* __restrict__ ovf, int* __restrict__ ovf_cnt,
    float* __restrict__ pooled) {
    __shared__ int s_cnt[N];
    __shared__ int s_w[16];
    __shared__ int s_n;
    __shared__ int s_ovf;
    const int b = blockIdx.x;
    const int t = threadIdx.x;
    const int bN = b * N;
    const unsigned char* mb = (const unsigned char*)mask;
    int mode;
    if (mb[0] == 0x80 && mb[1] == 0x3F) mode = 2;        // bf16
    else if (mb[0] != 0 && mb[1] != 0) mode = 0;         // bytes
    else if (mb[0] != 0) mode = (mb[4] != 0) ? 1 : 4;    // int32 : int64
    else mode = 3;                                       // f32
    int cnt = 0;
    if (mode == 0) {
        const unsigned char* r = mb + (size_t)b * N;
        for (int i = t; i < N; i += 1024) cnt += (r[i] != 0);
    } else if (mode == 1 || mode == 3) {
        const unsigned int* r = (const unsigned int*)mask + (size_t)b * N;
        for (int i = t; i < N; i += 1024) cnt += (r[i] != 0);
    } else if (mode == 2) {
        const unsigned short* r = (const unsigned short*)mask + (size_t)b * N;
        for (int i = t; i < N; i += 1024) cnt += (r[i] != 0);
    } else {
        const unsigned long long* r = (const unsigned long long*)mask + (size_t)b * N;
        for (int i = t; i < N; i += 1024) cnt += (r[i] != 0ULL);
    }
    for (int o = 32; o > 0; o >>= 1) cnt += __shfl_down(cnt, o);
    if ((t & 63) == 0) s_w[t >> 6] = cnt;
    for (int i = t; i < N; i += 1024) s_cnt[i] = 0;
    if (t == 0) s_ovf = 0;
    __syncthreads();
    if (t == 0) {
        int a = 0;
        for (int i = 0; i < 16; i++) a += s_w[i];
        s_n = a > N ? N : a;
    }
    __syncthreads();
    const int n = s_n;
    const int4* es4 = (const int4*)(eidx + (size_t)b * 2 * E);
    const int4* ed4 = es4 + E / 4;
    for (int i = t; i < E / 4; i += 1024) {
        int4 s4 = es4[i], d4 = ed4[i];
        if ((unsigned)s4.x < (unsigned)n && (unsigned)d4.x < (unsigned)n) atomicAdd(&s_cnt[d4.x], 1);
        if ((unsigned)s4.y < (unsigned)n && (unsigned)d4.y < (unsigned)n) atomicAdd(&s_cnt[d4.y], 1);
        if ((unsigned)s4.z < (unsigned)n && (unsigned)d4.z < (unsigned)n) atomicAdd(&s_cnt[d4.z], 1);
        if ((unsigned)s4.w < (unsigned)n && (unsigned)d4.w < (unsigned)n) atomicAdd(&s_cnt[d4.w], 1);
    }
    __syncthreads();
    for (int v = t; v < N; v += 1024) {
        int c = s_cnt[v];
        dis[bN + v] = (v < n) ? rsqrtf((float)(c + 1)) : 0.0f;
        degc[bN + v] = (unsigned char)(c < CAP ? c : CAP);
        s_cnt[v] = 0;
    }
    __syncthreads();
    for (int i = t; i < E / 4; i += 1024) {
        int4 s4 = es4[i], d4 = ed4[i];
#define FILL1(SS, DD)                                                          \
        if ((unsigned)(SS) < (unsigned)n && (unsigned)(DD) < (unsigned)n) {    \
            int pos = atomicAdd(&s_cnt[DD], 1);                                \
            if (pos < CAP)                                                     \
                ssrc[((size_t)(bN + (DD))) * CAP + pos] = (unsigned short)(SS);\
            else {                                                             \
                int oi = atomicAdd(&s_ovf, 1);                                 \
                if (oi < E) ovf[(size_t)b * E + oi] = make_int2((DD), (SS));   \
            }                                                                  \
        }
        FILL1(s4.x, d4.x) FILL1(s4.y, d4.y) FILL1(s4.z, d4.z) FILL1(s4.w, d4.w)
#undef FILL1
    }
    if (t == 0) { n_arr[b] = n; ovf_cnt[b] = s_ovf; }
    if (t < H) pooled[b * H + t] = 0.0f;
}

// ---------------------------------------------------------------------------
// K2: y = dis * x, packed bf16 pairs. F=32 -> 16 uints per node.
// ---------------------------------------------------------------------------
__global__ __launch_bounds__(256) void k_premult(
    const void* __restrict__ x, const int* __restrict__ bf16flag,
    const float* __restrict__ dis, unsigned int* __restrict__ y_u) {
    const int gid = blockIdx.x * 256 + threadIdx.x;  // B*N*16
    const int g = gid >> 4;
    const int f2 = gid & 15;
    const float dv = dis[g];
    float a, c;
    if (*bf16flag) {
        const unsigned short* xp = (const unsigned short*)x + (size_t)g * F + 2 * f2;
        a = b2f(xp[0]); c = b2f(xp[1]);
    } else {
        const float* xp = (const float*)x + (size_t)g * F + 2 * f2;
        a = xp[0]; c = xp[1];
    }
    y_u[gid] = pack2(a * dv, c * dv);
}

// ---------------------------------------------------------------------------
// K3: layer-1 gather (8 edges in flight: 2 predicated quad-slots per iter)
// + MFMA GEMM1 + relu + dis-premult -> z (bf16). XCD swizzle.
// ---------------------------------------------------------------------------
__global__ __launch_bounds__(256) void k_agg_gemm1(
    const unsigned int* __restrict__ y_u, const float* __restrict__ dis,
    const unsigned char* __restrict__ degc, const unsigned short* __restrict__ ssrc,
    const int2* __restrict__ ovf, const int* __restrict__ ovf_cnt,
    const unsigned short* __restrict__ w1t, const float* __restrict__ b1f,
    unsigned short* __restrict__ zs) {
    __shared__ unsigned short s_e[64 * CAP + 32];   // +pad: unrolled over-read
    __shared__ unsigned char s_dg[64];
    __shared__ float s_dv[64];
    __shared__ float s_b1[64];
    __shared__ __align__(16) unsigned short s_w1t[64 * 40];
    __shared__ __align__(16) unsigned short s_a1[64 * 40];
    const int bid = blockIdx.x;
    const int b = (bid & 7) + ((bid >> 8) << 3);
    const int v0 = ((bid >> 3) & 31) * 64;
    const int t = threadIdx.x;
    const int bN = b * N;
    if (t < 128) ((int4*)s_e)[t] = ((const int4*)(ssrc + (size_t)(bN + v0) * CAP))[t];
    if (t >= 128 && t < 144)
        ((unsigned int*)s_dg)[t - 128] = ((const unsigned int*)(degc + bN + v0))[t - 128];
    if (t >= 192) s_dv[t - 192] = dis[bN + v0 + (t - 192)];
    if (t >= 144 && t < 208) s_b1[t - 144] = b1f[t - 144];
    for (int i = t; i < 320; i += 256) ((int4*)s_w1t)[i] = ((const int4*)w1t)[i];
    __syncthreads();
    const int lane = t & 63;
    const int w = t >> 6;
    const int quad = lane >> 4;
    const int f2 = lane & 15;
    const int oc = ovf_cnt[b];
    const unsigned int* yb = y_u + (size_t)bN * (F / 2);
    for (int k = 0; k < 16; k++) {
        const int nn = w * 16 + k;
        const int v = v0 + nn;
        const int dg = s_dg[nn];
        const unsigned short* ep = &s_e[nn * CAP];
        float ax = 0.f, ay = 0.f;
        for (int s0 = 0; s0 < dg; s0 += 8) {   // wave-uniform bound, 8 in flight
            int sA = s0 + quad;
            int sB = s0 + 4 + quad;
            int iA = ep[sA] & (N - 1);
            int iB = ep[sB] & (N - 1);
            bool pA = sA < dg;
            bool pB = sB < dg;
            unsigned int uA = yb[(size_t)iA * (F / 2) + f2];
            unsigned int uB = yb[(size_t)iB * (F / 2) + f2];
            ax += pA ? __uint_as_float(uA << 16) : 0.0f;
            ay += pA ? __uint_as_float(uA & 0xffff0000u) : 0.0f;
            ax += pB ? __uint_as_float(uB << 16) : 0.0f;
            ay += pB ? __uint_as_float(uB & 0xffff0000u) : 0.0f;
        }
        ax += __shfl_xor(ax, 16); ay += __shfl_xor(ay, 16);
        ax += __shfl_xor(ax, 32); ay += __shfl_xor(ay, 32);
        if (quad == 0) {
            unsigned int u = yb[(size_t)v * (F / 2) + f2];  // self (premultiplied)
            ax += __uint_as_float(u << 16);
            ay += __uint_as_float(u & 0xffff0000u);
            if (oc > 0) {  // deg>CAP spills; ~never taken
                const int2* ob = ovf + (size_t)b * E;
                for (int j = 0; j < oc; j++) {
                    int2 o = ob[j];
                    if (o.x == v) {
                        unsigned int uo = yb[(size_t)o.y * (F / 2) + f2];
                        ax += __uint_as_float(uo << 16);
                        ay += __uint_as_float(uo & 0xffff0000u);
                    }
                }
            }
            float dv = s_dv[nn];
            *(unsigned int*)&s_a1[nn * 40 + 2 * f2] = pack2(ax * dv, ay * dv);
        }
    }
    __syncthreads();
    // MFMA GEMM1: wave w -> rows m0..m0+15 of (a1 @ W1)
    const int m0 = w * 16;
    bf16x8 af = *(const bf16x8*)&s_a1[(m0 + f2) * 40 + quad * 8];
    float dvr[4];
#pragma unroll
    for (int r = 0; r < 4; r++) dvr[r] = s_dv[m0 + quad * 4 + r];
#pragma unroll
    for (int nt = 0; nt < 4; nt++) {
        bf16x8 bf = *(const bf16x8*)&s_w1t[(nt * 16 + f2) * 40 + quad * 8];
        f32x4 acc = {0.f, 0.f, 0.f, 0.f};
        acc = __builtin_amdgcn_mfma_f32_16x16x32_bf16(af, bf, acc, 0, 0, 0);
        float bb = s_b1[nt * 16 + f2];
#pragma unroll
        for (int r = 0; r < 4; r++) {
            int row = m0 + quad * 4 + r;
            float val = dvr[r] * fmaxf(acc[r] + bb, 0.0f);
            zs[(size_t)(bN + v0 + row) * H + nt * 16 + f2] = f2b(val);
        }
    }
}

// ---------------------------------------------------------------------------
// K4: layer-2 gather (4 edges in flight: 2 predicated half-slots per iter)
// + MFMA GEMM2 + relu + pool. h2 never stored.
// ---------------------------------------------------------------------------
__global__ __launch_bounds__(256) void k_agg_gemm2_pool(
    const unsigned int* __restrict__ z_u, const float* __restrict__ dis,
    const unsigned char* __restrict__ degc, const unsigned short* __restrict__ ssrc,
    const int2* __restrict__ ovf, const int* __restrict__ ovf_cnt,
    const unsigned short* __restrict__ w2t, const float* __restrict__ b2f_,
    float* __restrict__ pooled) {
    __shared__ unsigned short s_e[64 * CAP + 32];   // +pad: unrolled over-read
    __shared__ unsigned char s_dg[64];
    __shared__ float s_dv[64];
    __shared__ float s_b2[64];
    __shared__ __align__(16) unsigned short s_w2t[64 * 72];
    __shared__ __align__(16) unsigned short s_a2[64 * 72];
    __shared__ float s_pool[4][64];
    const int bid = blockIdx.x;
    const int b = (bid & 7) + ((bid >> 8) << 3);
    const int v0 = ((bid >> 3) & 31) * 64;
    const int t = threadIdx.x;
    const int bN = b * N;
    if (t < 128) ((int4*)s_e)[t] = ((const int4*)(ssrc + (size_t)(bN + v0) * CAP))[t];
    if (t >= 128 && t < 144)
        ((unsigned int*)s_dg)[t - 128] = ((const unsigned int*)(degc + bN + v0))[t - 128];
    if (t >= 192) s_dv[t - 192] = dis[bN + v0 + (t - 192)];
    if (t >= 144 && t < 208) s_b2[t - 144] = b2f_[t - 144];
    for (int i = t; i < 576; i += 256) ((int4*)s_w2t)[i] = ((const int4*)w2t)[i];
    __syncthreads();
    const int lane = t & 63;
    const int w = t >> 6;
    const int half = lane >> 5;
    const int f2h = lane & 31;
    const int quad = lane >> 4;
    const int f2 = lane & 15;
    const int oc = ovf_cnt[b];
    const unsigned int* zb = z_u + (size_t)bN * (H / 2);
    for (int k = 0; k < 16; k++) {
        const int nn = w * 16 + k;
        const int v = v0 + nn;
        const int dg = s_dg[nn];
        const unsigned short* ep = &s_e[nn * CAP];
        float ax = 0.f, ay = 0.f;
        for (int s0 = 0; s0 < dg; s0 += 4) {   // wave-uniform bound, 4 in flight
            int sA = s0 + half;
            int sB = s0 + 2 + half;
            int iA = ep[sA] & (N - 1);
            int iB = ep[sB] & (N - 1);
            bool pA = sA < dg;
            bool pB = sB < dg;
            unsigned int uA = zb[(size_t)iA * (H / 2) + f2h];
            unsigned int uB = zb[(size_t)iB * (H / 2) + f2h];
            ax += pA ? __uint_as_float(uA << 16) : 0.0f;
            ay += pA ? __uint_as_float(uA & 0xffff0000u) : 0.0f;
            ax += pB ? __uint_as_float(uB << 16) : 0.0f;
            ay += pB ? __uint_as_float(uB & 0xffff0000u) : 0.0f;
        }
        ax += __shfl_xor(ax, 32); ay += __shfl_xor(ay, 32);
        if (half == 0) {
            unsigned int u = zb[(size_t)v * (H / 2) + f2h];  // self
            ax += __uint_as_float(u << 16);
            ay += __uint_as_float(u & 0xffff0000u);
            if (oc > 0) {
                const int2* ob = ovf + (size_t)b * E;
                for (int j = 0; j < oc; j++) {
                    int2 o = ob[j];
                    if (o.x == v) {
                        unsigned int uo = zb[(size_t)o.y * (H / 2) + f2h];
                        ax += __uint_as_float(uo << 16);
                        ay += __uint_as_float(uo & 0xffff0000u);
                    }
                }
            }
            float dv = s_dv[nn];
            *(unsigned int*)&s_a2[nn * 72 + 2 * f2h] = pack2(ax * dv, ay * dv);
        }
    }
    __syncthreads();
    // MFMA GEMM2 + pool
    const int m0 = w * 16;
    bf16x8 af0 = *(const bf16x8*)&s_a2[(m0 + f2) * 72 + quad * 8];
    bf16x8 af1 = *(const bf16x8*)&s_a2[(m0 + f2) * 72 + 32 + quad * 8];
    float dvr[4];
#pragma unroll
    for (int r = 0; r < 4; r++) dvr[r] = s_dv[m0 + quad * 4 + r];
#pragma unroll
    for (int nt = 0; nt < 4; nt++) {
        bf16x8 bf0 = *(const bf16x8*)&s_w2t[(nt * 16 + f2) * 72 + quad * 8];
        bf16x8 bf1 = *(const bf16x8*)&s_w2t[(nt * 16 + f2) * 72 + 32 + quad * 8];
        f32x4 acc = {0.f, 0.f, 0.f, 0.f};
        acc = __builtin_amdgcn_mfma_f32_16x16x32_bf16(af0, bf0, acc, 0, 0, 0);
        acc = __builtin_amdgcn_mfma_f32_16x16x32_bf16(af1, bf1, acc, 0, 0, 0);
        float bb = s_b2[nt * 16 + f2];
        float ps = 0.f;
#pragma unroll
        for (int r = 0; r < 4; r++)
            ps += (dvr[r] > 0.0f) ? fmaxf(acc[r] + bb, 0.0f) : 0.0f;
        ps += __shfl_xor(ps, 16);
        ps += __shfl_xor(ps, 32);
        if (quad == 0) s_pool[w][nt * 16 + f2] = ps;
    }
    __syncthreads();
    if (t < H)
        atomicAdd(&pooled[b * H + t],
                  s_pool[0][t] + s_pool[1][t] + s_pool[2][t] + s_pool[3][t]);
}

// ---------------------------------------------------------------------------
// K5: MLP head, one wave per batch.
// ---------------------------------------------------------------------------
__global__ __launch_bounds__(64) void k_mlp(
    const float* __restrict__ pooled, const int* __restrict__ n_arr,
    const float* __restrict__ aW1, const float* __restrict__ ab1,
    const float* __restrict__ aW2, const float* __restrict__ ab2,
    const int* __restrict__ flags, void* __restrict__ out) {
    const int b = blockIdx.x;
    const int t = threadIdx.x;
    __shared__ float p[64];
    __shared__ float hid[64];
    int n = n_arr[b];
    if (n < 1) n = 1;
    p[t] = pooled[b * H + t] / (float)n;
    __syncthreads();
    float acc = ab1[t];
    for (int j = 0; j < 64; j++) acc += p[j] * aW1[j * 64 + t];
    hid[t] = fmaxf(acc, 0.0f);
    __syncthreads();
    if (t < 16) {
        float a2 = ab2[t];
        for (int j = 0; j < 64; j++) a2 += hid[j] * aW2[j * 16 + t];
        if (flags[0]) ((unsigned short*)out)[b * OUTD + t] = f2b(a2);
        else          ((float*)out)[b * OUTD + t] = a2;
    }
}

// ---------------------------------------------------------------------------
extern "C" void kernel_launch(void* const* d_in, const int* in_sizes, int n_in,
                              void* d_out, int out_size, void* d_ws, size_t ws_size,
                              hipStream_t stream) {
    const void* x    = d_in[0];
    const int*  eidx = (const int*)d_in[1];
    const void* mask = d_in[2];

    char* ws = (char*)d_ws;
    size_t off = 0;
    auto alloc = [&](size_t bytes) -> void* {
        void* p = ws + off;
        off += (bytes + 255) & ~(size_t)255;
        return p;
    };
    int*   flags   = (int*)alloc(16 * sizeof(int));
    unsigned short* w1t = (unsigned short*)alloc(64 * 40 * 2);
    unsigned short* w2t = (unsigned short*)alloc(64 * 72 * 2);
    float* b1f     = (float*)alloc(H * sizeof(float));
    float* b2f_    = (float*)alloc(H * sizeof(float));
    float* aW1f    = (float*)alloc(H * H * sizeof(float));
    float* ab1f    = (float*)alloc(H * sizeof(float));
    float* aW2f    = (float*)alloc(H * OUTD * sizeof(float));
    float* ab2f    = (float*)alloc(OUTD * sizeof(float));
    int*   n_arr   = (int*)alloc(B * sizeof(int));
    float* dis     = (float*)alloc((size_t)B * N * sizeof(float));
    unsigned char*  degc = (unsigned char*)alloc((size_t)B * N);
    unsigned short* ssrc = (unsigned short*)alloc((size_t)B * N * CAP * 2);
    int2*  ovf     = (int2*)alloc((size_t)B * E * sizeof(int2));
    int*   ovf_cnt = (int*)alloc(B * sizeof(int));
    float* pooled  = (float*)alloc((size_t)B * H * sizeof(float));
    unsigned int* y_u = (unsigned int*)alloc((size_t)B * N * (F / 2) * 4);
    unsigned int* z_u = (unsigned int*)alloc((size_t)B * N * (H / 2) * 4);

    PrepArgs pa;
    pa.src[0] = x;        pa.dst[0] = pooled;  // dst[0] unused
    pa.src[1] = d_in[3];  pa.dst[1] = w1t;
    pa.src[2] = d_in[4];  pa.dst[2] = b1f;
    pa.src[3] = d_in[5];  pa.dst[3] = w2t;
    pa.src[4] = d_in[6];  pa.dst[4] = b2f_;
    pa.src[5] = d_in[7];  pa.dst[5] = aW1f;
    pa.src[6] = d_in[8];  pa.dst[6] = ab1f;
    pa.src[7] = d_in[9];  pa.dst[7] = aW2f;
    pa.src[8] = d_in[10]; pa.dst[8] = ab2f;

    k_prep<<<9, 256, 0, stream>>>(pa, flags);
    k_build<<<B, 1024, 0, stream>>>(eidx, mask, n_arr, dis, degc, ssrc, ovf,
                                    ovf_cnt, pooled);
    // y = dis * x (packed bf16, F=32)
    k_premult<<<(B * N * (F / 2)) / 256, 256, 0, stream>>>(x, flags, dis, y_u);
    // a1 = dis*(y[v]+sum y[s]); z = dis * relu(a1@W1 + b1)   [MFMA]
    k_agg_gemm1<<<B * 32, 256, 0, stream>>>(y_u, dis, degc, ssrc, ovf, ovf_cnt,
                                            w1t, b1f, (unsigned short*)z_u);
    // a2 = dis*(z[v]+sum z[s]); h2 = relu(a2@W2 + b2); pool  [MFMA]
    k_agg_gemm2_pool<<<B * 32, 256, 0, stream>>>(z_u, dis, degc, ssrc, ovf,
                                                 ovf_cnt, w2t, b2f_, pooled);
    // Head
    k_mlp<<<B, 64, 0, stream>>>(pooled, n_arr, aW1f, ab1f, aW2f, ab2f, flags, d_out);
}